// Round 7
// baseline (27453.217 us; speedup 1.0000x reference)
//
#include <hip/hip_runtime.h>
#include <hip/hip_fp16.h>

#define BB   64
#define TDEC 400
#define TENC 512
#define DD   256
#define PRE  128
#define NOUT 400
#define G3   768
#define C2E  2.8853900817779268f   // 2*log2(e): tanh(x) = 1 - 2/(exp2(C2E*x)+1)

typedef _Float16 h2_t __attribute__((ext_vector_type(2)));

// ---------------- fast math ----------------
__device__ __forceinline__ float fsig(float x) {
    return __builtin_amdgcn_rcpf(1.0f + __expf(-x));
}
__device__ __forceinline__ float ftanh(float x) {
    float t = __expf(2.0f * x);
    return 1.0f - 2.0f * __builtin_amdgcn_rcpf(t + 1.0f);
}
__device__ __forceinline__ float fexp2(float x) {
#if __has_builtin(__builtin_amdgcn_exp2f)
    return __builtin_amdgcn_exp2f(x);
#else
    return exp2f(x);
#endif
}
// 8-term fp16 x fp16 -> fp32 dot from two 16B packets
__device__ __forceinline__ float dot8(float4 w, float4 x, float acc) {
    union { float4 f; h2_t h[4]; } uw, ux;
    uw.f = w; ux.f = x;
#if __has_builtin(__builtin_amdgcn_fdot2)
    #pragma unroll
    for (int k = 0; k < 4; k++)
        acc = __builtin_amdgcn_fdot2(uw.h[k], ux.h[k], acc, false);
#else
    #pragma unroll
    for (int k = 0; k < 4; k++) {
        acc = fmaf((float)uw.h[k].x, (float)ux.h[k].x, acc);
        acc = fmaf((float)uw.h[k].y, (float)ux.h[k].y, acc);
    }
#endif
    return acc;
}

// ---------------- prenet: p_h = fp16(relu(relu(x@W1+b1)@W2+b2)) ----------------
__global__ __launch_bounds__(256) void prenet_kernel(
    const float* __restrict__ x, const float* __restrict__ W1, const float* __restrict__ b1,
    const float* __restrict__ W2, const float* __restrict__ b2, __half* __restrict__ p_h)
{
    __shared__ __align__(16) float xs[8][NOUT];
    __shared__ __align__(16) float hs[8][DD];
    const int row0 = blockIdx.x * 8;
    const int tid = threadIdx.x;
    for (int idx = tid; idx < 8 * NOUT; idx += 256) {
        int m = idx / NOUT, i = idx - m * NOUT;
        xs[m][i] = x[(size_t)(row0 + m) * NOUT + i];
    }
    __syncthreads();
    {
        const int j = tid;
        float acc[8];
        float bj = b1[j];
        #pragma unroll
        for (int m = 0; m < 8; m++) acc[m] = bj;
        #pragma unroll 4
        for (int i = 0; i < NOUT; i++) {
            float w = W1[i * DD + j];
            #pragma unroll
            for (int m = 0; m < 8; m++) acc[m] = fmaf(xs[m][i], w, acc[m]);
        }
        #pragma unroll
        for (int m = 0; m < 8; m++) hs[m][j] = fmaxf(acc[m], 0.0f);
    }
    __syncthreads();
    if (tid < PRE) {
        const int j = tid;
        float acc[8];
        float bj = b2[j];
        #pragma unroll
        for (int m = 0; m < 8; m++) acc[m] = bj;
        #pragma unroll 4
        for (int i = 0; i < DD; i++) {
            float w = W2[i * PRE + j];
            #pragma unroll
            for (int m = 0; m < 8; m++) acc[m] = fmaf(hs[m][i], w, acc[m]);
        }
        #pragma unroll
        for (int m = 0; m < 8; m++)
            p_h[(size_t)(row0 + m) * PRE + j] = __float2half(fmaxf(acc[m], 0.0f));
    }
}

// ---------------- gxp[b,t][j] = bi0[j] + p[b,t] @ k0_top  (loop-invariant GRU0 input) ----
__global__ __launch_bounds__(768) void gx0_kernel(
    const __half* __restrict__ p_h, const float* __restrict__ k0,
    const float* __restrict__ bi0, __half* __restrict__ gxp)
{
    __shared__ __align__(16) float ps[8][PRE];
    const int row0 = blockIdx.x * 8;
    const int tid = threadIdx.x;
    for (int idx = tid; idx < 8 * PRE; idx += 768) {
        int m = idx >> 7, i = idx & 127;
        ps[m][i] = __half2float(p_h[(size_t)(row0 + m) * PRE + i]);
    }
    __syncthreads();
    const int j = tid;
    float acc[8];
    float bj = bi0[j];
    #pragma unroll
    for (int m = 0; m < 8; m++) acc[m] = bj;
    #pragma unroll 4
    for (int i = 0; i < PRE; i++) {
        float w = k0[(size_t)i * G3 + j];   // k0 rows 0..127 = prenet part
        #pragma unroll
        for (int m = 0; m < 8; m++) acc[m] = fmaf(ps[m][i], w, acc[m]);
    }
    #pragma unroll
    for (int m = 0; m < 8; m++)
        gxp[(size_t)(row0 + m) * G3 + j] = __float2half(acc[m]);
}

// ---------------- keys (packed + pre-scaled): keys_p[b][(i8*512+e)*8+k] = fp16(C2E*(mem@Wm)[e][8i8+k])
__global__ __launch_bounds__(256) void keys_kernel(
    const float* __restrict__ mem, const float* __restrict__ Wm, __half* __restrict__ keys_p)
{
    __shared__ __align__(16) float xs[8][DD];
    const int row0 = blockIdx.x * 8;
    const int tid = threadIdx.x;
    for (int idx = tid; idx < 8 * DD; idx += 256) {
        int m = idx >> 8, i = idx & 255;
        xs[m][i] = mem[(size_t)(row0 + m) * DD + i];
    }
    __syncthreads();
    const int j = tid;
    const int i8 = j >> 3, k = j & 7;
    float acc[8] = {0.f,0.f,0.f,0.f,0.f,0.f,0.f,0.f};
    #pragma unroll 4
    for (int i = 0; i < DD; i++) {
        float w = Wm[i * DD + j];
        #pragma unroll
        for (int m = 0; m < 8; m++) acc[m] = fmaf(xs[m][i], w, acc[m]);
    }
    #pragma unroll
    for (int m = 0; m < 8; m++) {
        int r = row0 + m;
        int bb = r >> 9, e = r & 511;
        keys_p[(size_t)bb * (TENC * DD) + ((size_t)i8 * TENC + e) * 8 + k] =
            __float2half(C2E * acc[m]);
    }
}

// ---------------- weight pack: src[R][C] fp32 -> dst[(i8*C + j)*8 + k] = fp16 src[8*i8+k][j] ----------------
__global__ __launch_bounds__(256) void pack_w_kernel(
    const float* __restrict__ src, __half* __restrict__ dst, int R, int C)
{
    int flat = blockIdx.x * 256 + threadIdx.x;
    if (flat < R * C) {
        int k = flat & 7;
        int t2 = flat >> 3;
        int j = t2 % C;
        int i8 = t2 / C;
        dst[flat] = __float2half(src[(size_t)(8 * i8 + k) * C + j]);
    }
}

// ---------------- mem pack (8-wide): memq[b*16384 + e8*256 + d] = float4 of fp16 {mem[b][8e8+k][d]}k=0..7
__global__ __launch_bounds__(256) void pack_mem8_kernel(
    const float* __restrict__ mem, float4* __restrict__ dst)
{
    int flat = blockIdx.x * 256 + threadIdx.x;
    if (flat < BB * 64 * 256) {
        int d  = flat & 255;
        int e8 = (flat >> 8) & 63;
        int b  = flat >> 14;
        const float* base = mem + ((size_t)b * TENC + 8 * e8) * DD + d;
        union { float4 f; __half2 h[4]; } u;
        u.h[0] = __floats2half2_rn(base[0 * DD], base[1 * DD]);
        u.h[1] = __floats2half2_rn(base[2 * DD], base[3 * DD]);
        u.h[2] = __floats2half2_rn(base[4 * DD], base[5 * DD]);
        u.h[3] = __floats2half2_rn(base[6 * DD], base[7 * DD]);
        dst[flat] = u.f;
    }
}

// ---------------- y = ahist(fp16) @ Wo + bo ----------------
__global__ __launch_bounds__(448) void out_kernel(
    const __half* __restrict__ ah, const float* __restrict__ Wo, const float* __restrict__ bo,
    float* __restrict__ y)
{
    __shared__ __align__(16) float xs[8][DD];
    const int row0 = blockIdx.x * 8;
    const int tid = threadIdx.x;
    for (int idx = tid; idx < 8 * DD; idx += 448) {
        int m = idx >> 8, i = idx & 255;
        xs[m][i] = __half2float(ah[(size_t)(row0 + m) * DD + i]);
    }
    __syncthreads();
    if (tid < NOUT) {
        const int j = tid;
        float acc[8];
        float bj = bo[j];
        #pragma unroll
        for (int m = 0; m < 8; m++) acc[m] = bj;
        #pragma unroll 4
        for (int i = 0; i < DD; i++) {
            float w = Wo[i * NOUT + j];
            #pragma unroll
            for (int m = 0; m < 8; m++) acc[m] = fmaf(xs[m][i], w, acc[m]);
        }
        #pragma unroll
        for (int m = 0; m < 8; m++) y[(size_t)(row0 + m) * NOUT + j] = acc[m];
    }
}

// ---------------- decoder: 128 blocks (2 per batch elem) x 768 threads ----------------
// Pair split over e: block handles 256 of 512 encoder positions. Its keys (256e x 256d fp16 =
// 131 KB) live ENTIRELY in LDS -> zero keys traffic. Per-XCD L2 set = weights 1.97 MB +
// 16 x mem-half 131 KB ~= 4.0 MB -> mem L2-resident (R6's 5.1 MB thrashed -> 8 GB HBM refetch).
// GRU is replicated across the pair (bitwise identical -> deterministic); ONE exchange/step:
// unnormalized ctx-partial (1 KB) + exp-sum via parity-double-buffered mailbox + monotonic
// flag counters (device-scope atomics, __threadfence release/acquire). Pairs placed on the
// same XCD via idx%8 swizzle (placement heuristic only; correctness placement-independent).
#define SCORE_BODY(UK) do {                                              \
    float4 q0 = qp4[2 * i8], q1 = qp4[2 * i8 + 1];                       \
    float4 v0 = vp4[2 * i8], v1 = vp4[2 * i8 + 1];                       \
    float a0 = (float)UK.h[0].x + q0.x;                                  \
    float a1 = (float)UK.h[0].y + q0.y;                                  \
    float a2 = (float)UK.h[1].x + q0.z;                                  \
    float a3 = (float)UK.h[1].y + q0.w;                                  \
    float a4 = (float)UK.h[2].x + q1.x;                                  \
    float a5 = (float)UK.h[2].y + q1.y;                                  \
    float a6 = (float)UK.h[3].x + q1.z;                                  \
    float a7 = (float)UK.h[3].y + q1.w;                                  \
    accA = fmaf(v0.x, __builtin_amdgcn_rcpf(fexp2(a0) + 1.0f), accA);    \
    accB = fmaf(v0.y, __builtin_amdgcn_rcpf(fexp2(a1) + 1.0f), accB);    \
    accA = fmaf(v0.z, __builtin_amdgcn_rcpf(fexp2(a2) + 1.0f), accA);    \
    accB = fmaf(v0.w, __builtin_amdgcn_rcpf(fexp2(a3) + 1.0f), accB);    \
    accA = fmaf(v1.x, __builtin_amdgcn_rcpf(fexp2(a4) + 1.0f), accA);    \
    accB = fmaf(v1.y, __builtin_amdgcn_rcpf(fexp2(a5) + 1.0f), accB);    \
    accA = fmaf(v1.z, __builtin_amdgcn_rcpf(fexp2(a6) + 1.0f), accA);    \
    accB = fmaf(v1.w, __builtin_amdgcn_rcpf(fexp2(a7) + 1.0f), accB);    \
} while (0)

__global__ __launch_bounds__(768, 1) void decoder_kernel(
    const __half* __restrict__ gxp,  const __half* __restrict__ keys_p,
    const float4* __restrict__ memq,
    const __half* __restrict__ k0p,  const __half* __restrict__ r0p,
    const __half* __restrict__ k1p,  const __half* __restrict__ r1p,
    const __half* __restrict__ Wqp,  const __half* __restrict__ Wap,
    const float* __restrict__ br0,
    const float* __restrict__ bi1, const float* __restrict__ br1,
    const float* __restrict__ v,   __half* __restrict__ ahist,
    float* __restrict__ mboxC, float* __restrict__ mboxS,
    unsigned* __restrict__ flags)
{
    __shared__ __align__(16) float4 kAll[32 * 256];     // this half's keys, ALL d: 131 KB
    __shared__ __align__(16) __half xa[DD];
    __shared__ __align__(16) __half h0s[DD], h1s[DD];
    __shared__ __align__(16) __half ctxh[DD];
    __shared__ __align__(16) float h0f[DD], h1f[DD];
    __shared__ __align__(16) float qf[DD], vf[DD];      // q pre-scaled by C2E; v fp32
    __shared__ __align__(16) float gx[G3], gh[G3];
    __shared__ __align__(16) float sc[256];             // exp(score), own half
    __shared__ __align__(16) float hWa[DD];
    __shared__ __align__(16) float ctxp[3][DD];
    __shared__ __align__(16) float redd[8];

    const int tid = threadIdx.x;
    // pair mapping: blocks idx and idx+8 share an XCD (idx%8 placement assumption)
    const int idxb = blockIdx.x;
    const int g    = idxb >> 4;            // 0..7
    const int sub  = idxb & 15;
    const int who  = sub >> 3;             // 0/1 half of the pair
    const int b    = g * 8 + (sub & 7);    // batch elem 0..63
    const int eBase = who * 256;

    const float b0r_r = br0[tid];
    const float b1i_r = bi1[tid];
    const float b1r_r = br1[tid];
    if (tid < DD) {
        h0f[tid] = 0.0f; h1f[tid] = 0.0f;
        h0s[tid] = __float2half(0.0f); h1s[tid] = __float2half(0.0f);
        vf[tid] = v[tid];
        xa[tid] = __float2half(0.0f);
    }
    const __half*  keyb = keys_p + (size_t)b * TENC * DD;
    const float4*  kg4  = (const float4*)keyb;
    const float4*  mqb  = memq + (size_t)b * (TENC / 8) * DD;
    const __half*  gxb  = gxp + (size_t)b * TDEC * G3;

    float* mcOwn  = mboxC + ((size_t)(b * 2 + who) * 2) * 256;
    float* mcPeer = mboxC + ((size_t)(b * 2 + (who ^ 1)) * 2) * 256;
    float* msOwn  = mboxS + (b * 2 + who) * 2;
    float* msPeer = mboxS + (b * 2 + (who ^ 1)) * 2;
    unsigned* flagOwn  = flags + (b * 2 + who);
    unsigned* flagPeer = flags + (b * 2 + (who ^ 1));

    // ---- this half's keys (all 32 d-slices) -> LDS ----
    for (int i2 = tid; i2 < 32 * 256; i2 += 768) {
        int i8 = i2 >> 8, el = i2 & 255;
        kAll[i2] = kg4[i8 * TENC + eBase + el];
    }

    __half gpre = gxb[tid];
    __syncthreads();

    #pragma unroll 1
    for (int t = 0; t < TDEC; t++) {
        // ---- GRU0 gates (replicated on both blocks of the pair) ----
        {
            const float4* wpA = (const float4*)k0p;
            const float4* wpB = (const float4*)r0p;
            const float4* xp  = (const float4*)xa;
            const float4* hp  = (const float4*)h0s;
            float acc  = __half2float(gpre);
            if (t + 1 < TDEC) gpre = gxb[(size_t)(t + 1) * G3 + tid];
            float acc2 = b0r_r;
            #pragma unroll 4
            for (int i8 = 0; i8 < 32; i8++) {
                float4 x = xp[i8], h = hp[i8];
                acc  = dot8(wpA[(16 + i8) * G3 + tid], x, acc);
                acc2 = dot8(wpB[i8 * G3 + tid], h, acc2);
            }
            gx[tid] = acc; gh[tid] = acc2;
        }
        __syncthreads();
        if (tid < DD) {
            float z = fsig(gx[tid] + gh[tid]);
            float r = fsig(gx[DD + tid] + gh[DD + tid]);
            float cand = ftanh(gx[2 * DD + tid] + r * gh[2 * DD + tid]);
            float hn = z * h0f[tid] + (1.0f - z) * cand;
            h0f[tid] = hn; h0s[tid] = __float2half(hn);
        }
        __syncthreads();

        // ---- GRU1 gates ----
        {
            const float4* wpA = (const float4*)k1p;
            const float4* wpB = (const float4*)r1p;
            const float4* xp  = (const float4*)h0s;
            const float4* hp  = (const float4*)h1s;
            float acc  = b1i_r;
            float acc2 = b1r_r;
            #pragma unroll 4
            for (int i8 = 0; i8 < 32; i8++) {
                float4 x = xp[i8], h = hp[i8];
                acc  = dot8(wpA[i8 * G3 + tid], x, acc);
                acc2 = dot8(wpB[i8 * G3 + tid], h, acc2);
            }
            gx[tid] = acc; gh[tid] = acc2;
        }
        __syncthreads();
        if (tid < DD) {
            float z = fsig(gx[tid] + gh[tid]);
            float r = fsig(gx[DD + tid] + gh[DD + tid]);
            float cand = ftanh(gx[2 * DD + tid] + r * gh[2 * DD + tid]);
            float hn = z * h1f[tid] + (1.0f - z) * cand;
            h1f[tid] = hn; h1s[tid] = __float2half(hn);
        }
        __syncthreads();

        // ---- q = C2E*(h1n @ Wq) on tid 0..255 || hWa = h1n @ Wa_top on 256..511 ----
        if (tid < 256) {
            const float4* wp = (const float4*)Wqp;
            const float4* hp = (const float4*)h1s;
            float a0 = 0.0f, a1 = 0.0f;
            #pragma unroll 4
            for (int i8 = 0; i8 < 32; i8 += 2) {
                a0 = dot8(wp[i8 * DD + tid], hp[i8], a0);
                a1 = dot8(wp[(i8 + 1) * DD + tid], hp[i8 + 1], a1);
            }
            qf[tid] = C2E * (a0 + a1);
        } else if (tid < 512) {
            const int d = tid - 256;
            const float4* wp = (const float4*)Wap;
            const float4* hp = (const float4*)h1s;
            float a0 = 0.0f, a1 = 0.0f;
            #pragma unroll 4
            for (int i8 = 0; i8 < 32; i8 += 2) {
                a0 = dot8(wp[i8 * DD + d], hp[i8], a0);
                a1 = dot8(wp[(i8 + 1) * DD + d], hp[i8 + 1], a1);
            }
            hWa[d] = a0 + a1;
        }
        __syncthreads();

        // ---- scores: 2 threads per e (tid<512), keys 100% LDS ----
        if (tid < 512) {
            const int el   = tid >> 1;          // local e 0..255
            const int half = tid & 1;           // d-range half
            const float4* qp4 = (const float4*)qf;
            const float4* vp4 = (const float4*)vf;
            float accA = 0.0f, accB = 0.0f;
            const int i8s = half * 16;
            #pragma unroll 8
            for (int i8 = i8s; i8 < i8s + 16; i8++) {
                union { float4 f; h2_t h[4]; } uk;
                uk.f = kAll[i8 * 256 + el];
                SCORE_BODY(uk);
            }
            float tot = accA + accB;
            tot += __shfl_xor(tot, 1);          // combine d-halves within lane pair
            float wv = 0.0f;
            if (half == 0) {
                wv = __expf(-2.0f * tot);
                sc[el] = wv;
            }
            #pragma unroll
            for (int off = 32; off; off >>= 1) wv += __shfl_down(wv, off);
            if ((tid & 63) == 0) redd[tid >> 6] = wv;
        }
        __syncthreads();

        // ---- ctx partials over OWN 256 e (32 e8 chunks, 3-way split on 768 thr) ----
        {
            const int d  = tid & 255;
            const int ch = tid >> 8;
            const int e8s = (ch == 0) ? 0 : (ch == 1) ? 11 : 22;
            const int e8e = (ch == 0) ? 11 : (ch == 1) ? 22 : 32;
            const float4* scp = (const float4*)sc;
            float acc = 0.0f;
            #pragma unroll 2
            for (int e8 = e8s; e8 < e8e; e8++) {
                union { float4 f; __half2 h[4]; } um;
                um.f = mqb[(who * 32 + e8) * DD + d];
                float4 w0 = scp[2 * e8], w1 = scp[2 * e8 + 1];
                float2 f0 = __half22float2(um.h[0]), f1 = __half22float2(um.h[1]);
                float2 f2 = __half22float2(um.h[2]), f3 = __half22float2(um.h[3]);
                acc = fmaf(f0.x, w0.x, acc); acc = fmaf(f0.y, w0.y, acc);
                acc = fmaf(f1.x, w0.z, acc); acc = fmaf(f1.y, w0.w, acc);
                acc = fmaf(f2.x, w1.x, acc); acc = fmaf(f2.y, w1.y, acc);
                acc = fmaf(f3.x, w1.z, acc); acc = fmaf(f3.y, w1.w, acc);
            }
            ctxp[ch][d] = acc;
        }
        __syncthreads();

        // ---- publish own partial (parity slot), sync with partner, combine ----
        const int par = t & 1;
        float cOwn = 0.0f;
        if (tid < 256) {
            cOwn = ctxp[0][tid] + ctxp[1][tid] + ctxp[2][tid];
            mcOwn[par * 256 + tid] = cOwn;
        } else if (tid == 256) {
            msOwn[par] = ((redd[0] + redd[1]) + (redd[2] + redd[3]))
                       + ((redd[4] + redd[5]) + (redd[6] + redd[7]));
        }
        __syncthreads();
        __threadfence();                                   // release: mailbox before flag
        if (tid == 0) {
            atomicExch(flagOwn, (unsigned)(t + 1));
            while (atomicAdd(flagPeer, 0u) < (unsigned)(t + 1))
                __builtin_amdgcn_s_sleep(2);
        }
        __syncthreads();
        __threadfence();                                   // acquire: flag before mailbox
        if (tid < 256) {
            float cPeer = mcPeer[par * 256 + tid];
            float sPeer = msPeer[par];
            float sOwn  = ((redd[0] + redd[1]) + (redd[2] + redd[3]))
                        + ((redd[4] + redd[5]) + (redd[6] + redd[7]));
            float S = sOwn + sPeer;
            ctxh[tid] = __float2half((cOwn + cPeer) * __builtin_amdgcn_rcpf(S));
        }
        __syncthreads();

        // ---- attn = hWa + ctx @ Wa_bot (replicated); who==0 logs ahist ----
        if (tid < DD) {
            const float4* wp = (const float4*)Wap;
            const float4* cp = (const float4*)ctxh;
            float a0 = hWa[tid], a1 = 0.0f;
            #pragma unroll 4
            for (int i8 = 0; i8 < 32; i8 += 2) {
                a0 = dot8(wp[(32 + i8) * DD + tid], cp[i8], a0);
                a1 = dot8(wp[(33 + i8) * DD + tid], cp[i8 + 1], a1);
            }
            __half ah = __float2half(a0 + a1);
            xa[tid] = ah;
            if (who == 0) ahist[((size_t)b * TDEC + t) * DD + tid] = ah;
        }
        __syncthreads();
    }
}

extern "C" void kernel_launch(void* const* d_in, const int* in_sizes, int n_in,
                              void* d_out, int out_size, void* d_ws, size_t ws_size,
                              hipStream_t stream)
{
    const float* dec    = (const float*)d_in[0];
    const float* memory = (const float*)d_in[1];
    const float* W1  = (const float*)d_in[2];
    const float* b1  = (const float*)d_in[3];
    const float* W2  = (const float*)d_in[4];
    const float* b2  = (const float*)d_in[5];
    const float* k0  = (const float*)d_in[6];
    const float* r0  = (const float*)d_in[7];
    const float* bi0 = (const float*)d_in[8];
    const float* br0 = (const float*)d_in[9];
    const float* k1  = (const float*)d_in[10];
    const float* r1  = (const float*)d_in[11];
    const float* bi1 = (const float*)d_in[12];
    const float* br1 = (const float*)d_in[13];
    const float* Wq  = (const float*)d_in[14];
    const float* Wm  = (const float*)d_in[15];
    const float* v   = (const float*)d_in[16];
    const float* Wa  = (const float*)d_in[17];
    const float* Wo  = (const float*)d_in[18];
    const float* bo  = (const float*)d_in[19];
    float* out = (float*)d_out;
    (void)ws_size; (void)in_sizes; (void)n_in; (void)out_size;

    // ---- workspace layout (fp16 packs), ~94.7 MB ----
    char* w = (char*)d_ws;
    size_t off = 0;
    __half*  p_h    = (__half*)(w + off);  off += (size_t)BB * TDEC * PRE * 2;   // 6.55 MB
    __half*  keys_p = (__half*)(w + off);  off += (size_t)BB * TENC * DD * 2;    // 16.8 MB
    float4*  memq   = (float4*)(w + off);  off += (size_t)BB * TENC * DD * 2;    // 16.8 MB
    __half*  gxp    = (__half*)(w + off);  off += (size_t)BB * TDEC * G3 * 2;    // 39.3 MB
    __half*  k0p    = (__half*)(w + off);  off += (size_t)384 * G3 * 2;
    __half*  r0p    = (__half*)(w + off);  off += (size_t)DD * G3 * 2;
    __half*  k1p    = (__half*)(w + off);  off += (size_t)DD * G3 * 2;
    __half*  r1p    = (__half*)(w + off);  off += (size_t)DD * G3 * 2;
    __half*  Wqp    = (__half*)(w + off);  off += (size_t)DD * DD * 2;
    __half*  Wap    = (__half*)(w + off);  off += (size_t)2 * DD * DD * 2;
    __half*  ahist  = (__half*)(w + off);  off += (size_t)BB * TDEC * DD * 2;    // 13.1 MB

    // pair-exchange mailboxes alias the p_h region (p_h is dead once gx0_kernel has run)
    float*    mboxC = (float*)p_h;                   // 64*2*2*256 floats = 512 KB
    float*    mboxS = mboxC + (size_t)BB * 2 * 2 * 256;
    unsigned* flags = (unsigned*)(mboxS + BB * 2 * 2);  // 128 counters

    // precompute (all parallel, outside the recurrence)
    prenet_kernel<<<BB * TDEC / 8, 256, 0, stream>>>(dec, W1, b1, W2, b2, p_h);
    gx0_kernel<<<BB * TDEC / 8, 768, 0, stream>>>(p_h, k0, bi0, gxp);
    keys_kernel<<<BB * TENC / 8, 256, 0, stream>>>(memory, Wm, keys_p);
    pack_mem8_kernel<<<(BB * 64 * 256) / 256, 256, 0, stream>>>(memory, memq);
    pack_w_kernel<<<(384 * G3 + 255) / 256, 256, 0, stream>>>(k0, k0p, 384, G3);
    pack_w_kernel<<<(DD * G3 + 255) / 256, 256, 0, stream>>>(r0, r0p, DD, G3);
    pack_w_kernel<<<(DD * G3 + 255) / 256, 256, 0, stream>>>(k1, k1p, DD, G3);
    pack_w_kernel<<<(DD * G3 + 255) / 256, 256, 0, stream>>>(r1, r1p, DD, G3);
    pack_w_kernel<<<(DD * DD + 255) / 256, 256, 0, stream>>>(Wq, Wqp, DD, DD);
    pack_w_kernel<<<(2 * DD * DD + 255) / 256, 256, 0, stream>>>(Wa, Wap, 2 * DD, DD);

    // reset pair-sync flags (stream-ordered: runs after gx0_kernel consumed p_h)
    hipMemsetAsync(flags, 0, 2 * BB * sizeof(unsigned), stream);

    // the 400-step recurrence: 128 blocks, one CU pair per batch element
    decoder_kernel<<<2 * BB, 768, 0, stream>>>(gxp, keys_p, memq, k0p, r0p, k1p, r1p,
                                               Wqp, Wap, br0, bi1, br1, v, ahist,
                                               mboxC, mboxS, flags);

    // output projection (outside the recurrence)
    out_kernel<<<BB * TDEC / 8, 448, 0, stream>>>(ahist, Wo, bo, out);
}

// Round 8
// 12874.156 us; speedup vs baseline: 2.1324x; 2.1324x over previous
//
#include <hip/hip_runtime.h>
#include <hip/hip_fp16.h>

#define BB   64
#define TDEC 400
#define TENC 512
#define DD   256
#define PRE  128
#define NOUT 400
#define G3   768
#define C2E  2.8853900817779268f   // 2*log2(e): tanh(x) = 1 - 2/(exp2(C2E*x)+1)

typedef _Float16 h2_t __attribute__((ext_vector_type(2)));
typedef float f32x4_t __attribute__((ext_vector_type(4)));

// ---------------- fast math ----------------
__device__ __forceinline__ float fsig(float x) {
    return __builtin_amdgcn_rcpf(1.0f + __expf(-x));
}
__device__ __forceinline__ float ftanh(float x) {
    float t = __expf(2.0f * x);
    return 1.0f - 2.0f * __builtin_amdgcn_rcpf(t + 1.0f);
}
__device__ __forceinline__ float fexp2(float x) {
#if __has_builtin(__builtin_amdgcn_exp2f)
    return __builtin_amdgcn_exp2f(x);
#else
    return exp2f(x);
#endif
}
// non-temporal float4 load (mem stream: no reuse value, keep it out of the L2 set)
__device__ __forceinline__ float4 ntload4(const float4* p) {
    f32x4_t v = __builtin_nontemporal_load((const f32x4_t*)p);
    union { f32x4_t a; float4 b; } u; u.a = v; return u.b;
}
// 8-term fp16 x fp16 -> fp32 dot from two 16B packets
__device__ __forceinline__ float dot8(float4 w, float4 x, float acc) {
    union { float4 f; h2_t h[4]; } uw, ux;
    uw.f = w; ux.f = x;
#if __has_builtin(__builtin_amdgcn_fdot2)
    #pragma unroll
    for (int k = 0; k < 4; k++)
        acc = __builtin_amdgcn_fdot2(uw.h[k], ux.h[k], acc, false);
#else
    #pragma unroll
    for (int k = 0; k < 4; k++) {
        acc = fmaf((float)uw.h[k].x, (float)ux.h[k].x, acc);
        acc = fmaf((float)uw.h[k].y, (float)ux.h[k].y, acc);
    }
#endif
    return acc;
}

// ---------------- prenet: p_h = fp16(relu(relu(x@W1+b1)@W2+b2)) ----------------
__global__ __launch_bounds__(256) void prenet_kernel(
    const float* __restrict__ x, const float* __restrict__ W1, const float* __restrict__ b1,
    const float* __restrict__ W2, const float* __restrict__ b2, __half* __restrict__ p_h)
{
    __shared__ __align__(16) float xs[8][NOUT];
    __shared__ __align__(16) float hs[8][DD];
    const int row0 = blockIdx.x * 8;
    const int tid = threadIdx.x;
    for (int idx = tid; idx < 8 * NOUT; idx += 256) {
        int m = idx / NOUT, i = idx - m * NOUT;
        xs[m][i] = x[(size_t)(row0 + m) * NOUT + i];
    }
    __syncthreads();
    {
        const int j = tid;
        float acc[8];
        float bj = b1[j];
        #pragma unroll
        for (int m = 0; m < 8; m++) acc[m] = bj;
        #pragma unroll 4
        for (int i = 0; i < NOUT; i++) {
            float w = W1[i * DD + j];
            #pragma unroll
            for (int m = 0; m < 8; m++) acc[m] = fmaf(xs[m][i], w, acc[m]);
        }
        #pragma unroll
        for (int m = 0; m < 8; m++) hs[m][j] = fmaxf(acc[m], 0.0f);
    }
    __syncthreads();
    if (tid < PRE) {
        const int j = tid;
        float acc[8];
        float bj = b2[j];
        #pragma unroll
        for (int m = 0; m < 8; m++) acc[m] = bj;
        #pragma unroll 4
        for (int i = 0; i < DD; i++) {
            float w = W2[i * PRE + j];
            #pragma unroll
            for (int m = 0; m < 8; m++) acc[m] = fmaf(hs[m][i], w, acc[m]);
        }
        #pragma unroll
        for (int m = 0; m < 8; m++)
            p_h[(size_t)(row0 + m) * PRE + j] = __float2half(fmaxf(acc[m], 0.0f));
    }
}

// ---------------- gxp[b,t][j] = bi0[j] + p[b,t] @ k0_top  (loop-invariant GRU0 input) ----
__global__ __launch_bounds__(768) void gx0_kernel(
    const __half* __restrict__ p_h, const float* __restrict__ k0,
    const float* __restrict__ bi0, __half* __restrict__ gxp)
{
    __shared__ __align__(16) float ps[8][PRE];
    const int row0 = blockIdx.x * 8;
    const int tid = threadIdx.x;
    for (int idx = tid; idx < 8 * PRE; idx += 768) {
        int m = idx >> 7, i = idx & 127;
        ps[m][i] = __half2float(p_h[(size_t)(row0 + m) * PRE + i]);
    }
    __syncthreads();
    const int j = tid;
    float acc[8];
    float bj = bi0[j];
    #pragma unroll
    for (int m = 0; m < 8; m++) acc[m] = bj;
    #pragma unroll 4
    for (int i = 0; i < PRE; i++) {
        float w = k0[(size_t)i * G3 + j];   // k0 rows 0..127 = prenet part
        #pragma unroll
        for (int m = 0; m < 8; m++) acc[m] = fmaf(ps[m][i], w, acc[m]);
    }
    #pragma unroll
    for (int m = 0; m < 8; m++)
        gxp[(size_t)(row0 + m) * G3 + j] = __float2half(acc[m]);
}

// ---------------- keys (packed + pre-scaled): keys_p[b][(i8*512+e)*8+k] = fp16(C2E*(mem@Wm)[e][8i8+k])
// Packed layout: decoder reads slice i8 at [i8*512+e] -> 64 lanes x 16B contiguous (coalesced).
__global__ __launch_bounds__(256) void keys_kernel(
    const float* __restrict__ mem, const float* __restrict__ Wm, __half* __restrict__ keys_p)
{
    __shared__ __align__(16) float xs[8][DD];
    const int row0 = blockIdx.x * 8;
    const int tid = threadIdx.x;
    for (int idx = tid; idx < 8 * DD; idx += 256) {
        int m = idx >> 8, i = idx & 255;
        xs[m][i] = mem[(size_t)(row0 + m) * DD + i];
    }
    __syncthreads();
    const int j = tid;
    const int i8 = j >> 3, k = j & 7;
    float acc[8] = {0.f,0.f,0.f,0.f,0.f,0.f,0.f,0.f};
    #pragma unroll 4
    for (int i = 0; i < DD; i++) {
        float w = Wm[i * DD + j];
        #pragma unroll
        for (int m = 0; m < 8; m++) acc[m] = fmaf(xs[m][i], w, acc[m]);
    }
    #pragma unroll
    for (int m = 0; m < 8; m++) {
        int r = row0 + m;
        int bb = r >> 9, e = r & 511;
        keys_p[(size_t)bb * (TENC * DD) + ((size_t)i8 * TENC + e) * 8 + k] =
            __float2half(C2E * acc[m]);
    }
}

// ---------------- weight pack: src[R][C] fp32 -> dst[(i8*C + j)*8 + k] = fp16 src[8*i8+k][j] ----------------
__global__ __launch_bounds__(256) void pack_w_kernel(
    const float* __restrict__ src, __half* __restrict__ dst, int R, int C)
{
    int flat = blockIdx.x * 256 + threadIdx.x;
    if (flat < R * C) {
        int k = flat & 7;
        int t2 = flat >> 3;
        int j = t2 % C;
        int i8 = t2 / C;
        dst[flat] = __float2half(src[(size_t)(8 * i8 + k) * C + j]);
    }
}

// ---------------- mem pack (8-wide): memq[b*16384 + e8*256 + d] = float4 of fp16 {mem[b][8e8+k][d]}k=0..7
__global__ __launch_bounds__(256) void pack_mem8_kernel(
    const float* __restrict__ mem, float4* __restrict__ dst)
{
    int flat = blockIdx.x * 256 + threadIdx.x;
    if (flat < BB * 64 * 256) {
        int d  = flat & 255;
        int e8 = (flat >> 8) & 63;
        int b  = flat >> 14;
        const float* base = mem + ((size_t)b * TENC + 8 * e8) * DD + d;
        union { float4 f; __half2 h[4]; } u;
        u.h[0] = __floats2half2_rn(base[0 * DD], base[1 * DD]);
        u.h[1] = __floats2half2_rn(base[2 * DD], base[3 * DD]);
        u.h[2] = __floats2half2_rn(base[4 * DD], base[5 * DD]);
        u.h[3] = __floats2half2_rn(base[6 * DD], base[7 * DD]);
        dst[flat] = u.f;
    }
}

// ---------------- y = ahist(fp16) @ Wo + bo ----------------
__global__ __launch_bounds__(448) void out_kernel(
    const __half* __restrict__ ah, const float* __restrict__ Wo, const float* __restrict__ bo,
    float* __restrict__ y)
{
    __shared__ __align__(16) float xs[8][DD];
    const int row0 = blockIdx.x * 8;
    const int tid = threadIdx.x;
    for (int idx = tid; idx < 8 * DD; idx += 448) {
        int m = idx >> 8, i = idx & 255;
        xs[m][i] = __half2float(ah[(size_t)(row0 + m) * DD + i]);
    }
    __syncthreads();
    if (tid < NOUT) {
        const int j = tid;
        float acc[8];
        float bj = bo[j];
        #pragma unroll
        for (int m = 0; m < 8; m++) acc[m] = bj;
        #pragma unroll 4
        for (int i = 0; i < DD; i++) {
            float w = Wo[i * NOUT + j];
            #pragma unroll
            for (int m = 0; m < 8; m++) acc[m] = fmaf(xs[m][i], w, acc[m]);
        }
        #pragma unroll
        for (int m = 0; m < 8; m++) y[(size_t)(row0 + m) * NOUT + j] = acc[m];
    }
}

// ---------------- decoder: 64 blocks x 768 threads (12 waves); R6 structure + nt mem stream ----
// R6 diagnosis: dur == FETCH/598GB/s; 5.1 MB/XCD set (weights 1.97 + 8x[keys-low 131KB + mem
// 262KB]) thrashed L2 -> weights/keys refetched from HBM every step. R7's pair-split fixed the
// traffic but died on mailbox-sync convoy + LDS conflicts (counters: 1.3e8 conflicts, 14% VALU).
// This version: R6 + NON-TEMPORAL mem loads (ctx) so the 262KB/step stream evicts first.
// Protected L2 set = weights 1.97 MB + 8 x keys-low 131KB ~= 3.0 MB < 4 MB -> resident.
// Keys d>=128 in LDS (128 KB linear packed image); keys d<128 stream from (now-stable) L2.
#define SCORE_BODY(UK) do {                                              \
    float4 q0 = qp4[2 * i8], q1 = qp4[2 * i8 + 1];                       \
    float4 v0 = vp4[2 * i8], v1 = vp4[2 * i8 + 1];                       \
    float a0 = (float)UK.h[0].x + q0.x;                                  \
    float a1 = (float)UK.h[0].y + q0.y;                                  \
    float a2 = (float)UK.h[1].x + q0.z;                                  \
    float a3 = (float)UK.h[1].y + q0.w;                                  \
    float a4 = (float)UK.h[2].x + q1.x;                                  \
    float a5 = (float)UK.h[2].y + q1.y;                                  \
    float a6 = (float)UK.h[3].x + q1.z;                                  \
    float a7 = (float)UK.h[3].y + q1.w;                                  \
    accA = fmaf(v0.x, __builtin_amdgcn_rcpf(fexp2(a0) + 1.0f), accA);    \
    accB = fmaf(v0.y, __builtin_amdgcn_rcpf(fexp2(a1) + 1.0f), accB);    \
    accA = fmaf(v0.z, __builtin_amdgcn_rcpf(fexp2(a2) + 1.0f), accA);    \
    accB = fmaf(v0.w, __builtin_amdgcn_rcpf(fexp2(a3) + 1.0f), accB);    \
    accA = fmaf(v1.x, __builtin_amdgcn_rcpf(fexp2(a4) + 1.0f), accA);    \
    accB = fmaf(v1.y, __builtin_amdgcn_rcpf(fexp2(a5) + 1.0f), accB);    \
    accA = fmaf(v1.z, __builtin_amdgcn_rcpf(fexp2(a6) + 1.0f), accA);    \
    accB = fmaf(v1.w, __builtin_amdgcn_rcpf(fexp2(a7) + 1.0f), accB);    \
} while (0)

__global__ __launch_bounds__(768, 1) void decoder_kernel(
    const __half* __restrict__ gxp,  const __half* __restrict__ keys_p,
    const float4* __restrict__ memq,
    const __half* __restrict__ k0p,  const __half* __restrict__ r0p,
    const __half* __restrict__ k1p,  const __half* __restrict__ r1p,
    const __half* __restrict__ Wqp,  const __half* __restrict__ Wap,
    const float* __restrict__ br0,
    const float* __restrict__ bi1, const float* __restrict__ br1,
    const float* __restrict__ v,   __half* __restrict__ ahist)
{
    __shared__ __align__(16) float4 kLds4[16 * TENC];   // keys d in [128,256): 128 KB
    __shared__ __align__(16) __half xa[DD];             // att fp16 (prenet part precomputed)
    __shared__ __align__(16) __half h0s[DD], h1s[DD];   // state fp16 (dot operands)
    __shared__ __align__(16) __half ctxh[DD];
    __shared__ __align__(16) float h0f[DD], h1f[DD];    // state fp32 (exact carry)
    __shared__ __align__(16) float qf[DD], vf[DD];      // q pre-scaled by C2E; v fp32
    __shared__ __align__(16) float gx[G3], gh[G3];
    __shared__ __align__(16) float sc[TENC];            // exp(score)
    __shared__ __align__(16) float hWa[DD];             // h1 @ Wa_top
    __shared__ __align__(16) float ctxp[3][DD];         // ctx partials (3-way e-split)
    __shared__ __align__(16) float redd[16];

    const int tid = threadIdx.x;
    const int b = blockIdx.x;

    // biases in registers (one output j = tid per thread)
    const float b0r_r = br0[tid];
    const float b1i_r = bi1[tid];
    const float b1r_r = br1[tid];
    if (tid < DD) {
        h0f[tid] = 0.0f; h1f[tid] = 0.0f;
        h0s[tid] = __float2half(0.0f); h1s[tid] = __float2half(0.0f);
        vf[tid] = v[tid];
        xa[tid] = __float2half(0.0f);
    }
    const __half*  keyb = keys_p + (size_t)b * TENC * DD;
    const float4*  kg4  = (const float4*)keyb;          // global keys, slices 0..15
    const float4*  mqb  = memq + (size_t)b * (TENC / 8) * DD;
    const __half*  gxb  = gxp + (size_t)b * TDEC * G3;

    // ---- keys d>=128 (i8 16..31) -> LDS (linear copy of packed layout) ----
    {
        const float4* src = (const float4*)keyb;
        for (int idx = tid; idx < 16 * TENC; idx += 768)
            kLds4[idx] = src[16 * TENC + idx];
    }

    __half gpre = gxb[tid];             // prefetch gxp row for t=0 (one output per thread)
    __syncthreads();

    #pragma unroll 1
    for (int t = 0; t < TDEC; t++) {
        // ---- GRU0 gates: gx = gxp + att@k0_bot ; gh = h0@r0 + br0 (2 chains, 768 thr) ----
        {
            const float4* wpA = (const float4*)k0p;
            const float4* wpB = (const float4*)r0p;
            const float4* xp  = (const float4*)xa;
            const float4* hp  = (const float4*)h0s;
            float acc  = __half2float(gpre);
            if (t + 1 < TDEC) gpre = gxb[(size_t)(t + 1) * G3 + tid];  // prefetch next step
            float acc2 = b0r_r;
            #pragma unroll 4
            for (int i8 = 0; i8 < 32; i8++) {
                float4 x = xp[i8], h = hp[i8];
                acc  = dot8(wpA[(16 + i8) * G3 + tid], x, acc);   // att rows 128..383
                acc2 = dot8(wpB[i8 * G3 + tid], h, acc2);
            }
            gx[tid] = acc; gh[tid] = acc2;
        }
        __syncthreads();
        if (tid < DD) {
            float z = fsig(gx[tid] + gh[tid]);
            float r = fsig(gx[DD + tid] + gh[DD + tid]);
            float cand = ftanh(gx[2 * DD + tid] + r * gh[2 * DD + tid]);
            float hn = z * h0f[tid] + (1.0f - z) * cand;
            h0f[tid] = hn; h0s[tid] = __float2half(hn);
        }
        __syncthreads();

        // ---- GRU1 gates: gx = h0n@k1 + bi1 ; gh = h1@r1 + br1 ----
        {
            const float4* wpA = (const float4*)k1p;
            const float4* wpB = (const float4*)r1p;
            const float4* xp  = (const float4*)h0s;
            const float4* hp  = (const float4*)h1s;
            float acc  = b1i_r;
            float acc2 = b1r_r;
            #pragma unroll 4
            for (int i8 = 0; i8 < 32; i8++) {
                float4 x = xp[i8], h = hp[i8];
                acc  = dot8(wpA[i8 * G3 + tid], x, acc);
                acc2 = dot8(wpB[i8 * G3 + tid], h, acc2);
            }
            gx[tid] = acc; gh[tid] = acc2;
        }
        __syncthreads();
        if (tid < DD) {
            float z = fsig(gx[tid] + gh[tid]);
            float r = fsig(gx[DD + tid] + gh[DD + tid]);
            float cand = ftanh(gx[2 * DD + tid] + r * gh[2 * DD + tid]);
            float hn = z * h1f[tid] + (1.0f - z) * cand;
            h1f[tid] = hn; h1s[tid] = __float2half(hn);
        }
        __syncthreads();

        // ---- q = C2E*(h1n @ Wq) on tid 0..255 || hWa = h1n @ Wa_top on 256..511 ----
        if (tid < 256) {
            const float4* wp = (const float4*)Wqp;
            const float4* hp = (const float4*)h1s;
            float a0 = 0.0f, a1 = 0.0f;
            #pragma unroll 4
            for (int i8 = 0; i8 < 32; i8 += 2) {
                a0 = dot8(wp[i8 * DD + tid], hp[i8], a0);
                a1 = dot8(wp[(i8 + 1) * DD + tid], hp[i8 + 1], a1);
            }
            qf[tid] = C2E * (a0 + a1);
        } else if (tid < 512) {
            const int d = tid - 256;
            const float4* wp = (const float4*)Wap;
            const float4* hp = (const float4*)h1s;
            float a0 = 0.0f, a1 = 0.0f;
            #pragma unroll 4
            for (int i8 = 0; i8 < 32; i8 += 2) {
                a0 = dot8(wp[i8 * DD + d], hp[i8], a0);
                a1 = dot8(wp[(i8 + 1) * DD + d], hp[i8 + 1], a1);
            }
            hWa[d] = a0 + a1;
        }
        __syncthreads();

        // ---- scores: tid<512; keys slices 0..15 from (stable) L2, 16..31 from LDS ----
        // softmax shift-invariance: w_e = exp(-2 * sum_d v_d/(exp2(k'+q')+1))
        if (tid < TENC) {
            const float4* qp4 = (const float4*)qf;
            const float4* vp4 = (const float4*)vf;
            float accA = 0.0f, accB = 0.0f;
            #pragma unroll 8
            for (int i8 = 0; i8 < 16; i8++) {
                union { float4 f; h2_t h[4]; } uk;
                uk.f = kg4[i8 * TENC + tid];            // global: 64 lanes x 16B contiguous
                SCORE_BODY(uk);
            }
            #pragma unroll 4
            for (int i8 = 16; i8 < 32; i8++) {
                union { float4 f; h2_t h[4]; } uk;
                uk.f = kLds4[(i8 - 16) * TENC + tid];   // LDS: contiguous 16B/lane
                SCORE_BODY(uk);
            }
            float wv = __expf(-2.0f * (accA + accB));
            sc[tid] = wv;
            #pragma unroll
            for (int off = 32; off; off >>= 1) wv += __shfl_down(wv, off);
            if ((tid & 63) == 0) redd[tid >> 6] = wv;
        }
        __syncthreads();

        // ---- ctx partials: 3-way split over e (768 thr); NON-TEMPORAL 16B loads ----
        {
            const int d  = tid & 255;
            const int ch = tid >> 8;                        // wave-uniform (4 waves/chunk)
            const int e8s = (ch == 0) ? 0 : (ch == 1) ? 22 : 43;
            const int e8e = (ch == 0) ? 22 : (ch == 1) ? 43 : 64;
            const float4* scp = (const float4*)sc;
            float acc = 0.0f;
            #pragma unroll 2
            for (int e8 = e8s; e8 < e8e; e8++) {
                union { float4 f; __half2 h[4]; } um;
                um.f = ntload4(mqb + e8 * DD + d);          // nt: evict-first, protect L2 set
                float4 w0 = scp[2 * e8], w1 = scp[2 * e8 + 1];
                float2 f0 = __half22float2(um.h[0]), f1 = __half22float2(um.h[1]);
                float2 f2 = __half22float2(um.h[2]), f3 = __half22float2(um.h[3]);
                acc = fmaf(f0.x, w0.x, acc); acc = fmaf(f0.y, w0.y, acc);
                acc = fmaf(f1.x, w0.z, acc); acc = fmaf(f1.y, w0.w, acc);
                acc = fmaf(f2.x, w1.x, acc); acc = fmaf(f2.y, w1.y, acc);
                acc = fmaf(f3.x, w1.z, acc); acc = fmaf(f3.y, w1.w, acc);
            }
            ctxp[ch][d] = acc;
        }
        __syncthreads();

        // ---- combine partials + softmax denominator ----
        if (tid < DD) {
            const float4* rp = (const float4*)redd;
            float4 ra = rp[0], rb = rp[1];
            float ssum = ((ra.x + ra.y) + (ra.z + ra.w)) + ((rb.x + rb.y) + (rb.z + rb.w));
            float c = (ctxp[0][tid] + ctxp[1][tid] + ctxp[2][tid]) * __builtin_amdgcn_rcpf(ssum);
            ctxh[tid] = __float2half(c);
        }
        __syncthreads();

        // ---- attn = hWa + ctx @ Wa_bot ; carry (fp16) + nt log (write-only until out_kernel) ----
        if (tid < DD) {
            const float4* wp = (const float4*)Wap;
            const float4* cp = (const float4*)ctxh;
            float a0 = hWa[tid], a1 = 0.0f;
            #pragma unroll 4
            for (int i8 = 0; i8 < 32; i8 += 2) {
                a0 = dot8(wp[(32 + i8) * DD + tid], cp[i8], a0);
                a1 = dot8(wp[(33 + i8) * DD + tid], cp[i8 + 1], a1);
            }
            __half ah = __float2half(a0 + a1);
            xa[tid] = ah;
            __builtin_nontemporal_store(__half_as_ushort(ah),
                (unsigned short*)&ahist[((size_t)b * TDEC + t) * DD + tid]);
        }
        __syncthreads();
    }
}

extern "C" void kernel_launch(void* const* d_in, const int* in_sizes, int n_in,
                              void* d_out, int out_size, void* d_ws, size_t ws_size,
                              hipStream_t stream)
{
    const float* dec    = (const float*)d_in[0];
    const float* memory = (const float*)d_in[1];
    const float* W1  = (const float*)d_in[2];
    const float* b1  = (const float*)d_in[3];
    const float* W2  = (const float*)d_in[4];
    const float* b2  = (const float*)d_in[5];
    const float* k0  = (const float*)d_in[6];
    const float* r0  = (const float*)d_in[7];
    const float* bi0 = (const float*)d_in[8];
    const float* br0 = (const float*)d_in[9];
    const float* k1  = (const float*)d_in[10];
    const float* r1  = (const float*)d_in[11];
    const float* bi1 = (const float*)d_in[12];
    const float* br1 = (const float*)d_in[13];
    const float* Wq  = (const float*)d_in[14];
    const float* Wm  = (const float*)d_in[15];
    const float* v   = (const float*)d_in[16];
    const float* Wa  = (const float*)d_in[17];
    const float* Wo  = (const float*)d_in[18];
    const float* bo  = (const float*)d_in[19];
    float* out = (float*)d_out;
    (void)ws_size; (void)in_sizes; (void)n_in; (void)out_size;

    // ---- workspace layout (fp16 packs), ~94.7 MB ----
    char* w = (char*)d_ws;
    size_t off = 0;
    __half*  p_h    = (__half*)(w + off);  off += (size_t)BB * TDEC * PRE * 2;   // 6.55 MB
    __half*  keys_p = (__half*)(w + off);  off += (size_t)BB * TENC * DD * 2;    // 16.8 MB
    float4*  memq   = (float4*)(w + off);  off += (size_t)BB * TENC * DD * 2;    // 16.8 MB
    __half*  gxp    = (__half*)(w + off);  off += (size_t)BB * TDEC * G3 * 2;    // 39.3 MB
    __half*  k0p    = (__half*)(w + off);  off += (size_t)384 * G3 * 2;
    __half*  r0p    = (__half*)(w + off);  off += (size_t)DD * G3 * 2;
    __half*  k1p    = (__half*)(w + off);  off += (size_t)DD * G3 * 2;
    __half*  r1p    = (__half*)(w + off);  off += (size_t)DD * G3 * 2;
    __half*  Wqp    = (__half*)(w + off);  off += (size_t)DD * DD * 2;
    __half*  Wap    = (__half*)(w + off);  off += (size_t)2 * DD * DD * 2;
    __half*  ahist  = (__half*)(w + off);  off += (size_t)BB * TDEC * DD * 2;    // 13.1 MB

    // precompute (all parallel, outside the recurrence)
    prenet_kernel<<<BB * TDEC / 8, 256, 0, stream>>>(dec, W1, b1, W2, b2, p_h);
    gx0_kernel<<<BB * TDEC / 8, 768, 0, stream>>>(p_h, k0, bi0, gxp);
    keys_kernel<<<BB * TENC / 8, 256, 0, stream>>>(memory, Wm, keys_p);
    pack_mem8_kernel<<<(BB * 64 * 256) / 256, 256, 0, stream>>>(memory, memq);
    pack_w_kernel<<<(384 * G3 + 255) / 256, 256, 0, stream>>>(k0, k0p, 384, G3);
    pack_w_kernel<<<(DD * G3 + 255) / 256, 256, 0, stream>>>(r0, r0p, DD, G3);
    pack_w_kernel<<<(DD * G3 + 255) / 256, 256, 0, stream>>>(k1, k1p, DD, G3);
    pack_w_kernel<<<(DD * G3 + 255) / 256, 256, 0, stream>>>(r1, r1p, DD, G3);
    pack_w_kernel<<<(DD * DD + 255) / 256, 256, 0, stream>>>(Wq, Wqp, DD, DD);
    pack_w_kernel<<<(2 * DD * DD + 255) / 256, 256, 0, stream>>>(Wa, Wap, 2 * DD, DD);

    // the 400-step recurrence: one block per batch element; keys LDS + L2, mem nt-streamed
    decoder_kernel<<<BB, 768, 0, stream>>>(gxp, keys_p, memq, k0p, r0p, k1p, r1p,
                                           Wqp, Wap, br0, bi1, br1, v, ahist);

    // output projection (outside the recurrence)
    out_kernel<<<BB * TDEC / 8, 448, 0, stream>>>(ahist, Wo, bo, out);
}